// Round 10
// baseline (412.050 us; speedup 1.0000x reference)
//
#include <hip/hip_runtime.h>
#include <hip/hip_fp16.h>
#include <math.h>

#define N_NODES 100000
#define N_EDGES 1600000
#define F 128
#define NBUK 196        // ceil(N_NODES / 512)
#define BSH 9           // bucket = node >> 9  (512 nodes per bucket)
#define BSZ 512

typedef _Float16 half8 __attribute__((ext_vector_type(8)));
typedef float    f32x4 __attribute__((ext_vector_type(4)));

// ---------------------------------------------------------------- K1: bucket totals
__global__ __launch_bounds__(256) void hist_buckets(const int* __restrict__ src,
                                                    const int* __restrict__ dst,
                                                    int* __restrict__ totD,
                                                    int* __restrict__ totS)
{
    __shared__ int hd[NBUK], hs[NBUK];
    const int tid = threadIdx.x;
    if (tid < NBUK) { hd[tid] = 0; hs[tid] = 0; }
    __syncthreads();
    const int nt = gridDim.x * 256;
    const int n4 = N_EDGES / 4;
    for (int i = blockIdx.x * 256 + tid; i < n4; i += nt) {
        int4 d = reinterpret_cast<const int4*>(dst)[i];
        int4 s = reinterpret_cast<const int4*>(src)[i];
        atomicAdd(&hd[d.x >> BSH], 1); atomicAdd(&hd[d.y >> BSH], 1);
        atomicAdd(&hd[d.z >> BSH], 1); atomicAdd(&hd[d.w >> BSH], 1);
        atomicAdd(&hs[s.x >> BSH], 1); atomicAdd(&hs[s.y >> BSH], 1);
        atomicAdd(&hs[s.z >> BSH], 1); atomicAdd(&hs[s.w >> BSH], 1);
    }
    __syncthreads();
    if (tid < NBUK) {
        if (hd[tid]) atomicAdd(&totD[tid], hd[tid]);
        if (hs[tid]) atomicAdd(&totS[tid], hs[tid]);
    }
}

// ---------------------------------------------------------------- K2: scan totals
__global__ __launch_bounds__(256) void scan_buckets(const int* __restrict__ totD,
                                                    const int* __restrict__ totS,
                                                    int* __restrict__ baseD,
                                                    int* __restrict__ baseS,
                                                    int* __restrict__ curD,
                                                    int* __restrict__ curS)
{
    __shared__ int sd[256], ss[256];
    const int t = threadIdx.x;
    int vd = (t < NBUK) ? totD[t] : 0;
    int vs = (t < NBUK) ? totS[t] : 0;
    sd[t] = vd; ss[t] = vs;
    __syncthreads();
    for (int off = 1; off < 256; off <<= 1) {
        int ud = (t >= off) ? sd[t - off] : 0;
        int us = (t >= off) ? ss[t - off] : 0;
        __syncthreads();
        sd[t] += ud; ss[t] += us;
        __syncthreads();
    }
    if (t < NBUK) {
        baseD[t] = sd[t] - vd; curD[t] = sd[t] - vd;
        baseS[t] = ss[t] - vs; curS[t] = ss[t] - vs;
    }
    if (t == NBUK - 1) { baseD[NBUK] = sd[t]; baseS[NBUK] = ss[t]; }
}

// ---------------------------------------------------------------- K3: partition
// bukD packed: (d & 511) << 17 | s   (bucket implied by region; s < 2^17)
__global__ __launch_bounds__(512) void partition(const int* __restrict__ src,
                                                 const int* __restrict__ dst,
                                                 int* __restrict__ curD,
                                                 int* __restrict__ curS,
                                                 int* __restrict__ bukD,
                                                 int* __restrict__ bukS)
{
    __shared__ int hd[NBUK], hs[NBUK], bd[NBUK], bs[NBUK], cd[NBUK], cs[NBUK];
    const int tid = threadIdx.x;
    const int chunk = (N_EDGES + gridDim.x - 1) / gridDim.x;
    const int beg = blockIdx.x * chunk;
    const int end = min(beg + chunk, N_EDGES);
    if (tid < NBUK) { hd[tid] = 0; hs[tid] = 0; cd[tid] = 0; cs[tid] = 0; }
    __syncthreads();
    for (int e = beg + tid; e < end; e += 512) {
        atomicAdd(&hd[dst[e] >> BSH], 1);
        atomicAdd(&hs[src[e] >> BSH], 1);
    }
    __syncthreads();
    if (tid < NBUK) {
        bd[tid] = hd[tid] ? atomicAdd(&curD[tid], hd[tid]) : 0;
        bs[tid] = hs[tid] ? atomicAdd(&curS[tid], hs[tid]) : 0;
    }
    __syncthreads();
    for (int e = beg + tid; e < end; e += 512) {
        int d = dst[e], s = src[e];
        int bin = d >> BSH;
        int r = atomicAdd(&cd[bin], 1);
        bukD[bd[bin] + r] = ((d & 511) << 17) | s;
        int bin2 = s >> BSH;
        int r2 = atomicAdd(&cs[bin2], 1);
        bukS[bs[bin2] + r2] = s;
    }
}

// ---------------------------------------------------------------- K4: per-bucket CSR
__global__ __launch_bounds__(512) void csr_bucket(const int* __restrict__ bukD,
                                                  const int* __restrict__ baseD,
                                                  int* __restrict__ row_ptr,
                                                  float* __restrict__ sin_,
                                                  int* __restrict__ col)
{
    __shared__ int h[BSZ], sc[BSZ], cur[BSZ];
    const int tid = threadIdx.x;
    const int n0 = blockIdx.x << BSH;
    const int lo = baseD[blockIdx.x], hi = baseD[blockIdx.x + 1];
    h[tid] = 0;
    __syncthreads();
    for (int i = lo + tid; i < hi; i += 512)
        atomicAdd(&h[((unsigned)bukD[i]) >> 17], 1);
    __syncthreads();
    int own = h[tid];
    sc[tid] = own;
    __syncthreads();
    for (int off = 1; off < 512; off <<= 1) {
        int u = (tid >= off) ? sc[tid - off] : 0;
        __syncthreads();
        sc[tid] += u;
        __syncthreads();
    }
    int ex = sc[tid] - own;
    cur[tid] = ex;
    int node = n0 + tid;
    if (node <= N_NODES) row_ptr[node] = lo + ex;
    if (node < N_NODES)  sin_[node] = rsqrtf((float)max(own, 1));
    __syncthreads();
    for (int i = lo + tid; i < hi; i += 512) {
        int p = bukD[i];
        int r = atomicAdd(&cur[((unsigned)p) >> 17], 1);
        col[lo + r] = p & 0x1FFFF;
    }
}

// ---------------------------------------------------------------- K5: out-degree
__global__ __launch_bounds__(512) void deg_bucket(const int* __restrict__ bukS,
                                                  const int* __restrict__ baseS,
                                                  float* __restrict__ sout)
{
    __shared__ int h[BSZ];
    const int tid = threadIdx.x;
    const int n0 = blockIdx.x << BSH;
    const int lo = baseS[blockIdx.x], hi = baseS[blockIdx.x + 1];
    h[tid] = 0;
    __syncthreads();
    for (int i = lo + tid; i < hi; i += 512)
        atomicAdd(&h[bukS[i] - n0], 1);
    __syncthreads();
    int node = n0 + tid;
    if (node < N_NODES) sout[node] = rsqrtf((float)max(h[tid], 1));
}

// ---------------------------------------------------------------- pack W into B-fragment order (hi/lo fp16)
__global__ __launch_bounds__(256) void pack_w(const float* __restrict__ W,
                                              _Float16* __restrict__ hi,
                                              _Float16* __restrict__ lo)
{
    int idx = blockIdx.x * 256 + threadIdx.x;
    if (idx >= 16384) return;
    int f = idx >> 9, r = idx & 511;
    int l = r >> 3, j = r & 7;
    int kc = f >> 3, ct = f & 7;
    int k = kc * 32 + (l >> 4) * 8 + j;
    int n = ct * 16 + (l & 15);
    float w = W[k * 128 + n];
    _Float16 h = (_Float16)w;
    hi[idx] = h;
    lo[idx] = (_Float16)(w - (float)h);
}

// ---------------------------------------------------------------- MFMA GEMM, fp32 input (split hi/lo: 3 terms)
__global__ __launch_bounds__(256) void gemm_mfma_f32(const float* __restrict__ X,
                                                     const _Float16* __restrict__ Whi,
                                                     const _Float16* __restrict__ Wlo,
                                                     const float* __restrict__ srow,
                                                     _Float16* __restrict__ Y, int N)
{
    const int tid = threadIdx.x;
    const int l = tid & 63, w = tid >> 6;
    const int quad = l >> 4, m = l & 15;
    const int row0 = blockIdx.x * 128;
    const half8* Bh = reinterpret_cast<const half8*>(Whi);
    const half8* Bl = reinterpret_cast<const half8*>(Wlo);

    f32x4 acc[2][8] = {};

    for (int kc = 0; kc < 4; kc++) {
        half8 ah[2], al[2];
        #pragma unroll
        for (int rt = 0; rt < 2; rt++) {
            int grow = row0 + w * 32 + rt * 16 + m;
            float4 xa = make_float4(0.f, 0.f, 0.f, 0.f), xb = xa;
            if (grow < N) {
                const float4* Xp = reinterpret_cast<const float4*>(X) + (size_t)grow * 32 + kc * 8 + quad * 2;
                xa = Xp[0]; xb = Xp[1];
            }
            float xs[8] = {xa.x, xa.y, xa.z, xa.w, xb.x, xb.y, xb.z, xb.w};
            #pragma unroll
            for (int j = 0; j < 8; j++) {
                _Float16 h = (_Float16)xs[j];
                ah[rt][j] = h;
                al[rt][j] = (_Float16)(xs[j] - (float)h);
            }
        }
        #pragma unroll
        for (int ct = 0; ct < 8; ct++) {
            int f = kc * 8 + ct;
            half8 bh = Bh[f * 64 + l];
            half8 bl = Bl[f * 64 + l];
            #pragma unroll
            for (int rt = 0; rt < 2; rt++) {
                acc[rt][ct] = __builtin_amdgcn_mfma_f32_16x16x32_f16(ah[rt], bh, acc[rt][ct], 0, 0, 0);
                acc[rt][ct] = __builtin_amdgcn_mfma_f32_16x16x32_f16(al[rt], bh, acc[rt][ct], 0, 0, 0);
                acc[rt][ct] = __builtin_amdgcn_mfma_f32_16x16x32_f16(ah[rt], bl, acc[rt][ct], 0, 0, 0);
            }
        }
    }

    // C layout: col = l&15, row = quad*4 + reg
    #pragma unroll
    for (int rt = 0; rt < 2; rt++) {
        #pragma unroll
        for (int r = 0; r < 4; r++) {
            int grow = row0 + w * 32 + rt * 16 + quad * 4 + r;
            if (grow < N) {
                float s = srow[grow];
                #pragma unroll
                for (int ct = 0; ct < 8; ct++)
                    Y[(size_t)grow * 128 + ct * 16 + m] = (_Float16)(acc[rt][ct][r] * s);
            }
        }
    }
}

// ---------------------------------------------------------------- MFMA GEMM, fp16 input (exact: 2 terms)
__global__ __launch_bounds__(256) void gemm_mfma_f16(const _Float16* __restrict__ Xh,
                                                     const _Float16* __restrict__ Whi,
                                                     const _Float16* __restrict__ Wlo,
                                                     const float* __restrict__ srow,
                                                     _Float16* __restrict__ Y, int N)
{
    const int tid = threadIdx.x;
    const int l = tid & 63, w = tid >> 6;
    const int quad = l >> 4, m = l & 15;
    const int row0 = blockIdx.x * 128;
    const half8* Bh = reinterpret_cast<const half8*>(Whi);
    const half8* Bl = reinterpret_cast<const half8*>(Wlo);

    f32x4 acc[2][8] = {};

    for (int kc = 0; kc < 4; kc++) {
        half8 a[2];
        #pragma unroll
        for (int rt = 0; rt < 2; rt++) {
            int grow = row0 + w * 32 + rt * 16 + m;
            half8 z = {};
            a[rt] = (grow < N)
                ? *reinterpret_cast<const half8*>(Xh + (size_t)grow * 128 + kc * 32 + quad * 8)
                : z;
        }
        #pragma unroll
        for (int ct = 0; ct < 8; ct++) {
            int f = kc * 8 + ct;
            half8 bh = Bh[f * 64 + l];
            half8 bl = Bl[f * 64 + l];
            #pragma unroll
            for (int rt = 0; rt < 2; rt++) {
                acc[rt][ct] = __builtin_amdgcn_mfma_f32_16x16x32_f16(a[rt], bh, acc[rt][ct], 0, 0, 0);
                acc[rt][ct] = __builtin_amdgcn_mfma_f32_16x16x32_f16(a[rt], bl, acc[rt][ct], 0, 0, 0);
            }
        }
    }

    #pragma unroll
    for (int rt = 0; rt < 2; rt++) {
        #pragma unroll
        for (int r = 0; r < 4; r++) {
            int grow = row0 + w * 32 + rt * 16 + quad * 4 + r;
            if (grow < N) {
                float s = srow[grow];
                #pragma unroll
                for (int ct = 0; ct < 8; ct++)
                    Y[(size_t)grow * 128 + ct * 16 + m] = (_Float16)(acc[rt][ct][r] * s);
            }
        }
    }
}

// ---------------------------------------------------------------- gather-aggregate
// one wave per node, unroll-16 (16 x 256B rows in flight), zero-pad row N_NODES:
// Yh[n] = fp16( relu( (sum_{e} Hh[col[e]]) * sin_[n] + bias ) )
__global__ __launch_bounds__(256) void gather_agg(const __half* __restrict__ Hh,
                                                  const int* __restrict__ row_ptr,
                                                  const int* __restrict__ col,
                                                  const float* __restrict__ sin_,
                                                  const float* __restrict__ bias,
                                                  __half* __restrict__ Yh, int N)
{
    int node = blockIdx.x * 4 + (threadIdx.x >> 6);
    if (node >= N) return;
    int lane = threadIdx.x & 63;
    int beg = row_ptr[node], end = row_ptr[node + 1];
    const __half2* H2 = reinterpret_cast<const __half2*>(Hh);
    float2 acc = make_float2(0.f, 0.f);
    for (int i = beg; i < end; i += 16) {
        int c[16];
        #pragma unroll
        for (int j = 0; j < 16; j++)
            c[j] = (i + j < end) ? col[i + j] : N_NODES;   // pad -> zero row
        __half2 v[16];
        #pragma unroll
        for (int j = 0; j < 16; j++)
            v[j] = H2[(c[j] << 6) | lane];                 // 16 loads in flight
        #pragma unroll
        for (int j = 0; j < 16; j++) {
            float2 f = __half22float2(v[j]);
            acc.x += f.x; acc.y += f.y;
        }
    }
    float sc = sin_[node];
    float2 b = reinterpret_cast<const float2*>(bias)[lane];
    float ox = fmaxf(acc.x * sc + b.x, 0.f);
    float oy = fmaxf(acc.y * sc + b.y, 0.f);
    reinterpret_cast<__half2*>(Yh)[(node << 6) | lane] = __floats2half2_rn(ox, oy);
}

// ---------------------------------------------------------------- classifier (fp16 in)
__global__ __launch_bounds__(256) void classifier(const __half* __restrict__ Hh,
                                                  const float* __restrict__ Wc,
                                                  const float* __restrict__ bc,
                                                  float* __restrict__ out, int N)
{
    __shared__ float4 Wcs[128];   // row k -> 4 cols
    for (int i = threadIdx.x; i < 128; i += 256)
        Wcs[i] = reinterpret_cast<const float4*>(Wc)[i];
    __syncthreads();
    int i = blockIdx.x * 256 + threadIdx.x;
    if (i < N) {
        float4 acc = reinterpret_cast<const float4*>(bc)[0];
        const __half2* h2 = reinterpret_cast<const __half2*>(Hh) + (size_t)i * 64;
        #pragma unroll
        for (int j = 0; j < 64; j++) {
            float2 f = __half22float2(h2[j]);
            float4 w0 = Wcs[2 * j], w1 = Wcs[2 * j + 1];
            acc.x += f.x * w0.x + f.y * w1.x;
            acc.y += f.x * w0.y + f.y * w1.y;
            acc.z += f.x * w0.z + f.y * w1.z;
            acc.w += f.x * w0.w + f.y * w1.w;
        }
        reinterpret_cast<float4*>(out)[i] = acc;
    }
}

// ---------------------------------------------------------------- launch
extern "C" void kernel_launch(void* const* d_in, const int* in_sizes, int n_in,
                              void* d_out, int out_size, void* d_ws, size_t ws_size,
                              hipStream_t stream)
{
    const float* features = (const float*)d_in[0];
    const int*   src      = (const int*)d_in[1];
    const int*   dst      = (const int*)d_in[2];
    const float* W1       = (const float*)d_in[3];
    const float* b1       = (const float*)d_in[4];
    const float* W2       = (const float*)d_in[5];
    const float* b2       = (const float*)d_in[6];
    const float* Wc       = (const float*)d_in[7];
    const float* bc       = (const float*)d_in[8];
    float* out = (float*)d_out;

    char* ws = (char*)d_ws;
    const size_t MB = 1 << 20;
    int* totD  = (int*)(ws + 0);
    int* totS  = (int*)(ws + 1024);
    int* baseD = (int*)(ws + 2048);
    int* baseS = (int*)(ws + 3072);
    int* curD  = (int*)(ws + 4096);
    int* curS  = (int*)(ws + 5120);
    float* sout    = (float*)(ws + 1 * MB);          // N floats
    float* sin_    = (float*)(ws + 2 * MB);          // N floats
    int*   row_ptr = (int*)(ws + 3 * MB);            // N+1 ints
    int*   col     = (int*)(ws + 4 * MB);            // E ints (6.4 MB)
    int*   bukD    = (int*)(ws + 11 * MB);           // E packed ints (6.4 MB)
    int*   bukS    = (int*)(ws + 18 * MB);           // E ints (6.4 MB)
    _Float16* Whi1 = (_Float16*)(ws + 25 * MB);              // 32 KB
    _Float16* Wlo1 = (_Float16*)(ws + 25 * MB + 32 * 1024);  // 32 KB
    _Float16* Whi2 = (_Float16*)(ws + 25 * MB + 64 * 1024);  // 32 KB
    _Float16* Wlo2 = (_Float16*)(ws + 25 * MB + 96 * 1024);  // 32 KB
    _Float16* hMsg = (_Float16*)(ws + 26 * MB);      // [N+1,128] fp16 (25.6 MB + pad row)
    _Float16* hA   = (_Float16*)(ws + 52 * MB);      // [N,128] fp16 (25.6 MB)

    const int N = N_NODES;
    const int GBLK = (N + 127) / 128;                // 782

    // ---- CSR build + degree norms (bucket counting sort)
    hipMemsetAsync(ws, 0, 2048, stream);             // totD, totS
    hipMemsetAsync(hMsg + (size_t)N * F, 0, F * sizeof(_Float16), stream);  // zero pad row
    hist_buckets<<<392, 256, 0, stream>>>(src, dst, totD, totS);
    scan_buckets<<<1, 256, 0, stream>>>(totD, totS, baseD, baseS, curD, curS);
    partition<<<NBUK, 512, 0, stream>>>(src, dst, curD, curS, bukD, bukS);
    csr_bucket<<<NBUK, 512, 0, stream>>>(bukD, baseD, row_ptr, sin_, col);
    deg_bucket<<<NBUK, 512, 0, stream>>>(bukS, baseS, sout);

    // ---- pack weights into MFMA B-fragment order (fp16 hi/lo)
    pack_w<<<64, 256, 0, stream>>>(W1, Whi1, Wlo1);
    pack_w<<<64, 256, 0, stream>>>(W2, Whi2, Wlo2);

    // ---- layer 1
    gemm_mfma_f32<<<GBLK, 256, 0, stream>>>(features, Whi1, Wlo1, sout, hMsg, N);
    gather_agg<<<(N + 3) / 4, 256, 0, stream>>>((const __half*)hMsg, row_ptr, col, sin_, b1, (__half*)hA, N);

    // ---- layer 2
    gemm_mfma_f16<<<GBLK, 256, 0, stream>>>(hA, Whi2, Wlo2, sout, hMsg, N);
    gather_agg<<<(N + 3) / 4, 256, 0, stream>>>((const __half*)hMsg, row_ptr, col, sin_, b2, (__half*)hA, N);

    // ---- classifier
    classifier<<<(N + 255) / 256, 256, 0, stream>>>((const __half*)hA, Wc, bc, out, N);
}

// Round 11
// 354.925 us; speedup vs baseline: 1.1610x; 1.1610x over previous
//
#include <hip/hip_runtime.h>
#include <hip/hip_fp16.h>
#include <math.h>

#define N_NODES 100000
#define N_EDGES 1600000
#define F 128
#define NBUK 196        // ceil(N_NODES / 512)
#define BSH 9           // bucket = node >> 9  (512 nodes per bucket)
#define BSZ 512
#define CAP 9216        // fixed bucket region capacity (mean 8163, sd ~90)

typedef _Float16 half8 __attribute__((ext_vector_type(8)));
typedef float    f32x4 __attribute__((ext_vector_type(4)));

// ---------------------------------------------------------------- K0: init cursors + pad row
__global__ __launch_bounds__(256) void init_csr(int* __restrict__ curD,
                                                int* __restrict__ curS,
                                                _Float16* __restrict__ padrow)
{
    int t = threadIdx.x;
    if (t < NBUK) { curD[t] = t * CAP; curS[t] = t * CAP; }
    if (t < 16) reinterpret_cast<int4*>(padrow)[t] = make_int4(0, 0, 0, 0);
}

// ---------------------------------------------------------------- K1: partition (fixed-stride buckets)
// bukD packed: (d & 511) << 17 | s   (bucket implied by region; s < 2^17)
__global__ __launch_bounds__(512) void partition(const int* __restrict__ src,
                                                 const int* __restrict__ dst,
                                                 int* __restrict__ curD,
                                                 int* __restrict__ curS,
                                                 int* __restrict__ bukD,
                                                 int* __restrict__ bukS)
{
    __shared__ int hd[NBUK], hs[NBUK], bd[NBUK], bs[NBUK], cd[NBUK], cs[NBUK];
    const int tid = threadIdx.x;
    const int chunk = (((N_EDGES + NBUK - 1) / NBUK) + 3) & ~3;   // multiple of 4
    const int beg = blockIdx.x * chunk;
    const int end = min(beg + chunk, N_EDGES);
    if (beg >= end) return;
    if (tid < NBUK) { hd[tid] = 0; hs[tid] = 0; cd[tid] = 0; cs[tid] = 0; }
    __syncthreads();
    // pass 1: int4 histogram
    const int b4 = beg >> 2, e4 = end >> 2;   // beg,E multiples of 4
    for (int i = b4 + tid; i < e4; i += 512) {
        int4 d = reinterpret_cast<const int4*>(dst)[i];
        int4 s = reinterpret_cast<const int4*>(src)[i];
        atomicAdd(&hd[d.x >> BSH], 1); atomicAdd(&hd[d.y >> BSH], 1);
        atomicAdd(&hd[d.z >> BSH], 1); atomicAdd(&hd[d.w >> BSH], 1);
        atomicAdd(&hs[s.x >> BSH], 1); atomicAdd(&hs[s.y >> BSH], 1);
        atomicAdd(&hs[s.z >> BSH], 1); atomicAdd(&hs[s.w >> BSH], 1);
    }
    __syncthreads();
    if (tid < NBUK) {
        bd[tid] = hd[tid] ? atomicAdd(&curD[tid], hd[tid]) : 0;
        bs[tid] = hs[tid] ? atomicAdd(&curS[tid], hs[tid]) : 0;
    }
    __syncthreads();
    // pass 2: scatter into reserved runs
    for (int e = beg + tid; e < end; e += 512) {
        int d = dst[e], s = src[e];
        int bin = d >> BSH;
        int r = atomicAdd(&cd[bin], 1);
        bukD[bd[bin] + r] = ((d & 511) << 17) | s;
        int bin2 = s >> BSH;
        int r2 = atomicAdd(&cs[bin2], 1);
        bukS[bs[bin2] + r2] = s;
    }
}

// ---------------------------------------------------------------- K2: per-bucket CSR
__global__ __launch_bounds__(512) void csr_bucket(const int* __restrict__ bukD,
                                                  const int* __restrict__ curD,
                                                  int* __restrict__ row_ptr,
                                                  float* __restrict__ sin_,
                                                  int* __restrict__ col)
{
    __shared__ int h[BSZ], sc[BSZ], cur[BSZ];
    const int tid = threadIdx.x;
    const int n0 = blockIdx.x << BSH;
    const int lo = blockIdx.x * CAP, hi = curD[blockIdx.x];
    h[tid] = 0;
    __syncthreads();
    for (int i = lo + tid; i < hi; i += 512)
        atomicAdd(&h[((unsigned)bukD[i]) >> 17], 1);
    __syncthreads();
    int own = h[tid];
    sc[tid] = own;
    __syncthreads();
    for (int off = 1; off < 512; off <<= 1) {
        int u = (tid >= off) ? sc[tid - off] : 0;
        __syncthreads();
        sc[tid] += u;
        __syncthreads();
    }
    int ex = sc[tid] - own;
    cur[tid] = ex;
    int node = n0 + tid;
    if (node < N_NODES) {
        row_ptr[2 * node]     = lo + ex;        // beg
        row_ptr[2 * node + 1] = lo + ex + own;  // end
        sin_[node] = rsqrtf((float)max(own, 1));
    }
    __syncthreads();
    for (int i = lo + tid; i < hi; i += 512) {
        int p = bukD[i];
        int r = atomicAdd(&cur[((unsigned)p) >> 17], 1);
        col[lo + r] = p & 0x1FFFF;
    }
}

// ---------------------------------------------------------------- K3: out-degree
__global__ __launch_bounds__(512) void deg_bucket(const int* __restrict__ bukS,
                                                  const int* __restrict__ curS,
                                                  float* __restrict__ sout)
{
    __shared__ int h[BSZ];
    const int tid = threadIdx.x;
    const int n0 = blockIdx.x << BSH;
    const int lo = blockIdx.x * CAP, hi = curS[blockIdx.x];
    h[tid] = 0;
    __syncthreads();
    for (int i = lo + tid; i < hi; i += 512)
        atomicAdd(&h[bukS[i] - n0], 1);
    __syncthreads();
    int node = n0 + tid;
    if (node < N_NODES) sout[node] = rsqrtf((float)max(h[tid], 1));
}

// ---------------------------------------------------------------- pack W1+W2 into B-fragment order (hi/lo fp16)
__global__ __launch_bounds__(256) void pack_w2(const float* __restrict__ W1,
                                               const float* __restrict__ W2,
                                               _Float16* __restrict__ hi1,
                                               _Float16* __restrict__ lo1,
                                               _Float16* __restrict__ hi2,
                                               _Float16* __restrict__ lo2)
{
    int gidx = blockIdx.x * 256 + threadIdx.x;
    if (gidx >= 32768) return;
    const float* W = (gidx < 16384) ? W1 : W2;
    _Float16* hi = (gidx < 16384) ? hi1 : hi2;
    _Float16* lo = (gidx < 16384) ? lo1 : lo2;
    int idx = gidx & 16383;
    int f = idx >> 9, r = idx & 511;
    int l = r >> 3, j = r & 7;
    int kc = f >> 3, ct = f & 7;
    int k = kc * 32 + (l >> 4) * 8 + j;
    int n = ct * 16 + (l & 15);
    float w = W[k * 128 + n];
    _Float16 h = (_Float16)w;
    hi[idx] = h;
    lo[idx] = (_Float16)(w - (float)h);
}

// ---------------------------------------------------------------- MFMA GEMM, fp32 input (split hi/lo: 3 terms)
__global__ __launch_bounds__(256) void gemm_mfma_f32(const float* __restrict__ X,
                                                     const _Float16* __restrict__ Whi,
                                                     const _Float16* __restrict__ Wlo,
                                                     const float* __restrict__ srow,
                                                     _Float16* __restrict__ Y, int N)
{
    const int tid = threadIdx.x;
    const int l = tid & 63, w = tid >> 6;
    const int quad = l >> 4, m = l & 15;
    const int row0 = blockIdx.x * 128;
    const half8* Bh = reinterpret_cast<const half8*>(Whi);
    const half8* Bl = reinterpret_cast<const half8*>(Wlo);

    f32x4 acc[2][8] = {};

    for (int kc = 0; kc < 4; kc++) {
        half8 ah[2], al[2];
        #pragma unroll
        for (int rt = 0; rt < 2; rt++) {
            int grow = row0 + w * 32 + rt * 16 + m;
            float4 xa = make_float4(0.f, 0.f, 0.f, 0.f), xb = xa;
            if (grow < N) {
                const float4* Xp = reinterpret_cast<const float4*>(X) + (size_t)grow * 32 + kc * 8 + quad * 2;
                xa = Xp[0]; xb = Xp[1];
            }
            float xs[8] = {xa.x, xa.y, xa.z, xa.w, xb.x, xb.y, xb.z, xb.w};
            #pragma unroll
            for (int j = 0; j < 8; j++) {
                _Float16 h = (_Float16)xs[j];
                ah[rt][j] = h;
                al[rt][j] = (_Float16)(xs[j] - (float)h);
            }
        }
        #pragma unroll
        for (int ct = 0; ct < 8; ct++) {
            int f = kc * 8 + ct;
            half8 bh = Bh[f * 64 + l];
            half8 bl = Bl[f * 64 + l];
            #pragma unroll
            for (int rt = 0; rt < 2; rt++) {
                acc[rt][ct] = __builtin_amdgcn_mfma_f32_16x16x32_f16(ah[rt], bh, acc[rt][ct], 0, 0, 0);
                acc[rt][ct] = __builtin_amdgcn_mfma_f32_16x16x32_f16(al[rt], bh, acc[rt][ct], 0, 0, 0);
                acc[rt][ct] = __builtin_amdgcn_mfma_f32_16x16x32_f16(ah[rt], bl, acc[rt][ct], 0, 0, 0);
            }
        }
    }

    // C layout: col = l&15, row = quad*4 + reg
    #pragma unroll
    for (int rt = 0; rt < 2; rt++) {
        #pragma unroll
        for (int r = 0; r < 4; r++) {
            int grow = row0 + w * 32 + rt * 16 + quad * 4 + r;
            if (grow < N) {
                float s = srow[grow];
                #pragma unroll
                for (int ct = 0; ct < 8; ct++)
                    Y[(size_t)grow * 128 + ct * 16 + m] = (_Float16)(acc[rt][ct][r] * s);
            }
        }
    }
}

// ---------------------------------------------------------------- MFMA GEMM, fp16 input (exact: 2 terms)
__global__ __launch_bounds__(256) void gemm_mfma_f16(const _Float16* __restrict__ Xh,
                                                     const _Float16* __restrict__ Whi,
                                                     const _Float16* __restrict__ Wlo,
                                                     const float* __restrict__ srow,
                                                     _Float16* __restrict__ Y, int N)
{
    const int tid = threadIdx.x;
    const int l = tid & 63, w = tid >> 6;
    const int quad = l >> 4, m = l & 15;
    const int row0 = blockIdx.x * 128;
    const half8* Bh = reinterpret_cast<const half8*>(Whi);
    const half8* Bl = reinterpret_cast<const half8*>(Wlo);

    f32x4 acc[2][8] = {};

    for (int kc = 0; kc < 4; kc++) {
        half8 a[2];
        #pragma unroll
        for (int rt = 0; rt < 2; rt++) {
            int grow = row0 + w * 32 + rt * 16 + m;
            half8 z = {};
            a[rt] = (grow < N)
                ? *reinterpret_cast<const half8*>(Xh + (size_t)grow * 128 + kc * 32 + quad * 8)
                : z;
        }
        #pragma unroll
        for (int ct = 0; ct < 8; ct++) {
            int f = kc * 8 + ct;
            half8 bh = Bh[f * 64 + l];
            half8 bl = Bl[f * 64 + l];
            #pragma unroll
            for (int rt = 0; rt < 2; rt++) {
                acc[rt][ct] = __builtin_amdgcn_mfma_f32_16x16x32_f16(a[rt], bh, acc[rt][ct], 0, 0, 0);
                acc[rt][ct] = __builtin_amdgcn_mfma_f32_16x16x32_f16(a[rt], bl, acc[rt][ct], 0, 0, 0);
            }
        }
    }

    #pragma unroll
    for (int rt = 0; rt < 2; rt++) {
        #pragma unroll
        for (int r = 0; r < 4; r++) {
            int grow = row0 + w * 32 + rt * 16 + quad * 4 + r;
            if (grow < N) {
                float s = srow[grow];
                #pragma unroll
                for (int ct = 0; ct < 8; ct++)
                    Y[(size_t)grow * 128 + ct * 16 + m] = (_Float16)(acc[rt][ct][r] * s);
            }
        }
    }
}

// ---------------------------------------------------------------- gather-aggregate (round-8 form: unroll-4 + tail)
// one wave per node: Yh[n] = fp16( relu( (sum_{e} Hh[col[e]]) * sin_[n] + bias ) )
// row_ptr is [beg,end) pairs (2*node, 2*node+1)
__global__ __launch_bounds__(256) void gather_agg(const __half* __restrict__ Hh,
                                                  const int* __restrict__ row_ptr,
                                                  const int* __restrict__ col,
                                                  const float* __restrict__ sin_,
                                                  const float* __restrict__ bias,
                                                  __half* __restrict__ Yh, int N)
{
    int node = blockIdx.x * 4 + (threadIdx.x >> 6);
    if (node >= N) return;
    int lane = threadIdx.x & 63;
    int beg = row_ptr[2 * node], end = row_ptr[2 * node + 1];
    const __half2* H2 = reinterpret_cast<const __half2*>(Hh);
    float2 acc0 = make_float2(0.f, 0.f);
    float2 acc1 = make_float2(0.f, 0.f);
    int i = beg;
    for (; i + 3 < end; i += 4) {
        int s0 = col[i], s1 = col[i + 1], s2 = col[i + 2], s3 = col[i + 3];
        __half2 v0 = H2[((size_t)s0 << 6) | lane];
        __half2 v1 = H2[((size_t)s1 << 6) | lane];
        __half2 v2 = H2[((size_t)s2 << 6) | lane];
        __half2 v3 = H2[((size_t)s3 << 6) | lane];
        float2 f0 = __half22float2(v0), f1 = __half22float2(v1);
        float2 f2 = __half22float2(v2), f3 = __half22float2(v3);
        acc0.x += f0.x + f1.x; acc0.y += f0.y + f1.y;
        acc1.x += f2.x + f3.x; acc1.y += f2.y + f3.y;
    }
    for (; i < end; i++) {
        int s = col[i];
        float2 f = __half22float2(H2[((size_t)s << 6) | lane]);
        acc0.x += f.x; acc0.y += f.y;
    }
    float sc = sin_[node];
    float2 b = reinterpret_cast<const float2*>(bias)[lane];
    float ox = fmaxf((acc0.x + acc1.x) * sc + b.x, 0.f);
    float oy = fmaxf((acc0.y + acc1.y) * sc + b.y, 0.f);
    reinterpret_cast<__half2*>(Yh)[((size_t)node << 6) | lane] = __floats2half2_rn(ox, oy);
}

// ---------------------------------------------------------------- classifier (fp16 in)
__global__ __launch_bounds__(256) void classifier(const __half* __restrict__ Hh,
                                                  const float* __restrict__ Wc,
                                                  const float* __restrict__ bc,
                                                  float* __restrict__ out, int N)
{
    __shared__ float4 Wcs[128];   // row k -> 4 cols
    for (int i = threadIdx.x; i < 128; i += 256)
        Wcs[i] = reinterpret_cast<const float4*>(Wc)[i];
    __syncthreads();
    int i = blockIdx.x * 256 + threadIdx.x;
    if (i < N) {
        float4 acc = reinterpret_cast<const float4*>(bc)[0];
        const __half2* h2 = reinterpret_cast<const __half2*>(Hh) + (size_t)i * 64;
        #pragma unroll
        for (int j = 0; j < 64; j++) {
            float2 f = __half22float2(h2[j]);
            float4 w0 = Wcs[2 * j], w1 = Wcs[2 * j + 1];
            acc.x += f.x * w0.x + f.y * w1.x;
            acc.y += f.x * w0.y + f.y * w1.y;
            acc.z += f.x * w0.z + f.y * w1.z;
            acc.w += f.x * w0.w + f.y * w1.w;
        }
        reinterpret_cast<float4*>(out)[i] = acc;
    }
}

// ---------------------------------------------------------------- launch
extern "C" void kernel_launch(void* const* d_in, const int* in_sizes, int n_in,
                              void* d_out, int out_size, void* d_ws, size_t ws_size,
                              hipStream_t stream)
{
    const float* features = (const float*)d_in[0];
    const int*   src      = (const int*)d_in[1];
    const int*   dst      = (const int*)d_in[2];
    const float* W1       = (const float*)d_in[3];
    const float* b1       = (const float*)d_in[4];
    const float* W2       = (const float*)d_in[5];
    const float* b2       = (const float*)d_in[6];
    const float* Wc       = (const float*)d_in[7];
    const float* bc       = (const float*)d_in[8];
    float* out = (float*)d_out;

    char* ws = (char*)d_ws;
    const size_t MB = 1 << 20;
    int* curD  = (int*)(ws + 0);                     // NBUK ints
    int* curS  = (int*)(ws + 1024);                  // NBUK ints
    float* sout    = (float*)(ws + 1 * MB);          // N floats
    float* sin_    = (float*)(ws + 2 * MB);          // N floats
    int*   row_ptr = (int*)(ws + 3 * MB);            // 2N ints (beg/end pairs, 800 KB)
    int*   col     = (int*)(ws + 4 * MB);            // NBUK*CAP ints (7.2 MB, strided)
    int*   bukD    = (int*)(ws + 12 * MB);           // NBUK*CAP packed ints (7.2 MB)
    int*   bukS    = (int*)(ws + 20 * MB);           // NBUK*CAP ints (7.2 MB)
    _Float16* Whi1 = (_Float16*)(ws + 28 * MB);              // 32 KB
    _Float16* Wlo1 = (_Float16*)(ws + 28 * MB + 32 * 1024);  // 32 KB
    _Float16* Whi2 = (_Float16*)(ws + 28 * MB + 64 * 1024);  // 32 KB
    _Float16* Wlo2 = (_Float16*)(ws + 28 * MB + 96 * 1024);  // 32 KB
    _Float16* hMsg = (_Float16*)(ws + 29 * MB);      // [N+1,128] fp16 (25.6 MB + pad row)
    _Float16* hA   = (_Float16*)(ws + 55 * MB);      // [N,128] fp16 (25.6 MB)

    const int N = N_NODES;
    const int GBLK = (N + 127) / 128;                // 782

    // ---- CSR build + degree norms (fixed-stride bucket counting sort)
    init_csr<<<1, 256, 0, stream>>>(curD, curS, hMsg + (size_t)N * F);
    partition<<<NBUK, 512, 0, stream>>>(src, dst, curD, curS, bukD, bukS);
    csr_bucket<<<NBUK, 512, 0, stream>>>(bukD, curD, row_ptr, sin_, col);
    deg_bucket<<<NBUK, 512, 0, stream>>>(bukS, curS, sout);

    // ---- pack weights into MFMA B-fragment order (fp16 hi/lo)
    pack_w2<<<128, 256, 0, stream>>>(W1, W2, Whi1, Wlo1, Whi2, Wlo2);

    // ---- layer 1
    gemm_mfma_f32<<<GBLK, 256, 0, stream>>>(features, Whi1, Wlo1, sout, hMsg, N);
    gather_agg<<<(N + 3) / 4, 256, 0, stream>>>((const __half*)hMsg, row_ptr, col, sin_, b1, (__half*)hA, N);

    // ---- layer 2
    gemm_mfma_f16<<<GBLK, 256, 0, stream>>>(hA, Whi2, Wlo2, sout, hMsg, N);
    gather_agg<<<(N + 3) / 4, 256, 0, stream>>>((const __half*)hMsg, row_ptr, col, sin_, b2, (__half*)hA, N);

    // ---- classifier
    classifier<<<(N + 255) / 256, 256, 0, stream>>>((const __half*)hA, Wc, bc, out, N);
}

// Round 12
// 343.353 us; speedup vs baseline: 1.2001x; 1.0337x over previous
//
#include <hip/hip_runtime.h>
#include <hip/hip_fp16.h>
#include <math.h>

#define N_NODES 100000
#define N_EDGES 1600000
#define F 128
#define NBUK 196        // ceil(N_NODES / 512)
#define BSH 9           // bucket = node >> 9  (512 nodes per bucket)
#define BSZ 512
#define CAP 9216        // fixed bucket region capacity (mean 8163, sd ~90)

typedef _Float16 half8 __attribute__((ext_vector_type(8)));
typedef float    f32x4 __attribute__((ext_vector_type(4)));

// ---------------------------------------------------------------- K1: init cursors + pad row + pack W1/W2
// bid 0: init; bid 1..128: pack 32768 elements of W1|W2 into B-fragment order (hi/lo)
__global__ __launch_bounds__(256) void init_pack(int* __restrict__ curD,
                                                 int* __restrict__ curS,
                                                 _Float16* __restrict__ padrow,
                                                 const float* __restrict__ W1,
                                                 const float* __restrict__ W2,
                                                 _Float16* __restrict__ hi1,
                                                 _Float16* __restrict__ lo1,
                                                 _Float16* __restrict__ hi2,
                                                 _Float16* __restrict__ lo2)
{
    int t = threadIdx.x;
    if (blockIdx.x == 0) {
        if (t < NBUK) { curD[t] = t * CAP; curS[t] = t * CAP; }
        if (t < 16) reinterpret_cast<int4*>(padrow)[t] = make_int4(0, 0, 0, 0);
        return;
    }
    int gidx = (blockIdx.x - 1) * 256 + t;
    const float* W = (gidx < 16384) ? W1 : W2;
    _Float16* hi = (gidx < 16384) ? hi1 : hi2;
    _Float16* lo = (gidx < 16384) ? lo1 : lo2;
    int idx = gidx & 16383;
    int f = idx >> 9, r = idx & 511;
    int l = r >> 3, j = r & 7;
    int kc = f >> 3, ct = f & 7;
    int k = kc * 32 + (l >> 4) * 8 + j;
    int n = ct * 16 + (l & 15);
    float w = W[k * 128 + n];
    _Float16 h = (_Float16)w;
    hi[idx] = h;
    lo[idx] = (_Float16)(w - (float)h);
}

// ---------------------------------------------------------------- K2: partition (196 blocks) + gemm1 unscaled (391 blocks)
// partition: bukD packed (d&511)<<17 | s ; gemm1: Yh = fp16(X @ W1), fp32-exact fp16x3
__global__ __launch_bounds__(512) void part_gemm1(const int* __restrict__ src,
                                                  const int* __restrict__ dst,
                                                  int* __restrict__ curD,
                                                  int* __restrict__ curS,
                                                  int* __restrict__ bukD,
                                                  int* __restrict__ bukS,
                                                  const float* __restrict__ X,
                                                  const _Float16* __restrict__ Whi,
                                                  const _Float16* __restrict__ Wlo,
                                                  _Float16* __restrict__ Y, int N)
{
    __shared__ int hd[NBUK], hs[NBUK], bd[NBUK], bs[NBUK], cd[NBUK], cs[NBUK];
    const int tid = threadIdx.x;

    if (blockIdx.x < NBUK) {
        // ---------------- partition ----------------
        const int chunk = (((N_EDGES + NBUK - 1) / NBUK) + 3) & ~3;
        const int beg = blockIdx.x * chunk;
        const int end = min(beg + chunk, N_EDGES);
        if (beg >= end) return;
        if (tid < NBUK) { hd[tid] = 0; hs[tid] = 0; cd[tid] = 0; cs[tid] = 0; }
        __syncthreads();
        const int b4 = beg >> 2, e4 = end >> 2;
        for (int i = b4 + tid; i < e4; i += 512) {
            int4 d = reinterpret_cast<const int4*>(dst)[i];
            int4 s = reinterpret_cast<const int4*>(src)[i];
            atomicAdd(&hd[d.x >> BSH], 1); atomicAdd(&hd[d.y >> BSH], 1);
            atomicAdd(&hd[d.z >> BSH], 1); atomicAdd(&hd[d.w >> BSH], 1);
            atomicAdd(&hs[s.x >> BSH], 1); atomicAdd(&hs[s.y >> BSH], 1);
            atomicAdd(&hs[s.z >> BSH], 1); atomicAdd(&hs[s.w >> BSH], 1);
        }
        __syncthreads();
        if (tid < NBUK) {
            bd[tid] = hd[tid] ? atomicAdd(&curD[tid], hd[tid]) : 0;
            bs[tid] = hs[tid] ? atomicAdd(&curS[tid], hs[tid]) : 0;
        }
        __syncthreads();
        for (int e = beg + tid; e < end; e += 512) {
            int d = dst[e], s = src[e];
            int bin = d >> BSH;
            int r = atomicAdd(&cd[bin], 1);
            bukD[bd[bin] + r] = ((d & 511) << 17) | s;
            int bin2 = s >> BSH;
            int r2 = atomicAdd(&cs[bin2], 1);
            bukS[bs[bin2] + r2] = s;
        }
        return;
    }

    // ---------------- gemm1 (unscaled): 512 thr = 8 waves x 32 rows = 256 rows ----------------
    const int l = tid & 63, w = tid >> 6;
    const int quad = l >> 4, m = l & 15;
    const int row0 = (blockIdx.x - NBUK) * 256;
    const half8* Bh = reinterpret_cast<const half8*>(Whi);
    const half8* Bl = reinterpret_cast<const half8*>(Wlo);

    f32x4 acc[2][8] = {};

    for (int kc = 0; kc < 4; kc++) {
        half8 ah[2], al[2];
        #pragma unroll
        for (int rt = 0; rt < 2; rt++) {
            int grow = row0 + w * 32 + rt * 16 + m;
            float4 xa = make_float4(0.f, 0.f, 0.f, 0.f), xb = xa;
            if (grow < N) {
                const float4* Xp = reinterpret_cast<const float4*>(X) + (size_t)grow * 32 + kc * 8 + quad * 2;
                xa = Xp[0]; xb = Xp[1];
            }
            float xs[8] = {xa.x, xa.y, xa.z, xa.w, xb.x, xb.y, xb.z, xb.w};
            #pragma unroll
            for (int j = 0; j < 8; j++) {
                _Float16 h = (_Float16)xs[j];
                ah[rt][j] = h;
                al[rt][j] = (_Float16)(xs[j] - (float)h);
            }
        }
        #pragma unroll
        for (int ct = 0; ct < 8; ct++) {
            int f = kc * 8 + ct;
            half8 bh = Bh[f * 64 + l];
            half8 bl = Bl[f * 64 + l];
            #pragma unroll
            for (int rt = 0; rt < 2; rt++) {
                acc[rt][ct] = __builtin_amdgcn_mfma_f32_16x16x32_f16(ah[rt], bh, acc[rt][ct], 0, 0, 0);
                acc[rt][ct] = __builtin_amdgcn_mfma_f32_16x16x32_f16(al[rt], bh, acc[rt][ct], 0, 0, 0);
                acc[rt][ct] = __builtin_amdgcn_mfma_f32_16x16x32_f16(ah[rt], bl, acc[rt][ct], 0, 0, 0);
            }
        }
    }

    // C layout: col = l&15, row = quad*4 + reg
    #pragma unroll
    for (int rt = 0; rt < 2; rt++) {
        #pragma unroll
        for (int r = 0; r < 4; r++) {
            int grow = row0 + w * 32 + rt * 16 + quad * 4 + r;
            if (grow < N) {
                #pragma unroll
                for (int ct = 0; ct < 8; ct++)
                    Y[(size_t)grow * 128 + ct * 16 + m] = (_Float16)(acc[rt][ct][r]);
            }
        }
    }
}

// ---------------------------------------------------------------- K3: csr (bid<196) + out-degree (bid>=196)
__global__ __launch_bounds__(512) void csr_deg(const int* __restrict__ bukD,
                                               const int* __restrict__ bukS,
                                               const int* __restrict__ curD,
                                               const int* __restrict__ curS,
                                               int* __restrict__ row_ptr,
                                               float* __restrict__ sin_,
                                               float* __restrict__ sout,
                                               int* __restrict__ col)
{
    __shared__ int h[BSZ], sc[BSZ], cur[BSZ];
    const int tid = threadIdx.x;

    if (blockIdx.x >= NBUK) {
        // ---- out-degree from bukS ----
        const int bid = blockIdx.x - NBUK;
        const int n0 = bid << BSH;
        const int lo = bid * CAP, hi = curS[bid];
        h[tid] = 0;
        __syncthreads();
        for (int i = lo + tid; i < hi; i += 512)
            atomicAdd(&h[bukS[i] - n0], 1);
        __syncthreads();
        int node = n0 + tid;
        if (node < N_NODES) sout[node] = rsqrtf((float)max(h[tid], 1));
        return;
    }

    // ---- per-bucket CSR ----
    const int n0 = blockIdx.x << BSH;
    const int lo = blockIdx.x * CAP, hi = curD[blockIdx.x];
    h[tid] = 0;
    __syncthreads();
    for (int i = lo + tid; i < hi; i += 512)
        atomicAdd(&h[((unsigned)bukD[i]) >> 17], 1);
    __syncthreads();
    int own = h[tid];
    sc[tid] = own;
    __syncthreads();
    for (int off = 1; off < 512; off <<= 1) {
        int u = (tid >= off) ? sc[tid - off] : 0;
        __syncthreads();
        sc[tid] += u;
        __syncthreads();
    }
    int ex = sc[tid] - own;
    cur[tid] = ex;
    int node = n0 + tid;
    if (node < N_NODES) {
        row_ptr[2 * node]     = lo + ex;
        row_ptr[2 * node + 1] = lo + ex + own;
        sin_[node] = rsqrtf((float)max(own, 1));
    }
    __syncthreads();
    for (int i = lo + tid; i < hi; i += 512) {
        int p = bukD[i];
        int r = atomicAdd(&cur[((unsigned)p) >> 17], 1);
        col[lo + r] = p & 0x1FFFF;
    }
}

// ---------------------------------------------------------------- gather-aggregate layer 1 (per-edge sout scale)
// Yh[n] = fp16( relu( (sum_e sout[col[e]] * Hh[col[e]]) * sin_[n] + bias ) )
__global__ __launch_bounds__(256) void gather_agg_s(const __half* __restrict__ Hh,
                                                    const int* __restrict__ row_ptr,
                                                    const int* __restrict__ col,
                                                    const float* __restrict__ sout,
                                                    const float* __restrict__ sin_,
                                                    const float* __restrict__ bias,
                                                    __half* __restrict__ Yh, int N)
{
    int node = blockIdx.x * 4 + (threadIdx.x >> 6);
    if (node >= N) return;
    int lane = threadIdx.x & 63;
    int beg = row_ptr[2 * node], end = row_ptr[2 * node + 1];
    const __half2* H2 = reinterpret_cast<const __half2*>(Hh);
    float2 acc0 = make_float2(0.f, 0.f);
    float2 acc1 = make_float2(0.f, 0.f);
    int i = beg;
    for (; i + 3 < end; i += 4) {
        int s0 = col[i], s1 = col[i + 1], s2 = col[i + 2], s3 = col[i + 3];
        float w0 = sout[s0], w1 = sout[s1], w2 = sout[s2], w3 = sout[s3];
        __half2 v0 = H2[((size_t)s0 << 6) | lane];
        __half2 v1 = H2[((size_t)s1 << 6) | lane];
        __half2 v2 = H2[((size_t)s2 << 6) | lane];
        __half2 v3 = H2[((size_t)s3 << 6) | lane];
        float2 f0 = __half22float2(v0), f1 = __half22float2(v1);
        float2 f2 = __half22float2(v2), f3 = __half22float2(v3);
        acc0.x = fmaf(w0, f0.x, fmaf(w1, f1.x, acc0.x));
        acc0.y = fmaf(w0, f0.y, fmaf(w1, f1.y, acc0.y));
        acc1.x = fmaf(w2, f2.x, fmaf(w3, f3.x, acc1.x));
        acc1.y = fmaf(w2, f2.y, fmaf(w3, f3.y, acc1.y));
    }
    for (; i < end; i++) {
        int s = col[i];
        float w = sout[s];
        float2 f = __half22float2(H2[((size_t)s << 6) | lane]);
        acc0.x = fmaf(w, f.x, acc0.x);
        acc0.y = fmaf(w, f.y, acc0.y);
    }
    float sc = sin_[node];
    float2 b = reinterpret_cast<const float2*>(bias)[lane];
    float ox = fmaxf((acc0.x + acc1.x) * sc + b.x, 0.f);
    float oy = fmaxf((acc0.y + acc1.y) * sc + b.y, 0.f);
    reinterpret_cast<__half2*>(Yh)[((size_t)node << 6) | lane] = __floats2half2_rn(ox, oy);
}

// ---------------------------------------------------------------- MFMA GEMM, fp16 input, sout-scaled output (layer 2)
__global__ __launch_bounds__(256) void gemm_mfma_f16(const _Float16* __restrict__ Xh,
                                                     const _Float16* __restrict__ Whi,
                                                     const _Float16* __restrict__ Wlo,
                                                     const float* __restrict__ srow,
                                                     _Float16* __restrict__ Y, int N)
{
    const int tid = threadIdx.x;
    const int l = tid & 63, w = tid >> 6;
    const int quad = l >> 4, m = l & 15;
    const int row0 = blockIdx.x * 128;
    const half8* Bh = reinterpret_cast<const half8*>(Whi);
    const half8* Bl = reinterpret_cast<const half8*>(Wlo);

    f32x4 acc[2][8] = {};

    for (int kc = 0; kc < 4; kc++) {
        half8 a[2];
        #pragma unroll
        for (int rt = 0; rt < 2; rt++) {
            int grow = row0 + w * 32 + rt * 16 + m;
            half8 z = {};
            a[rt] = (grow < N)
                ? *reinterpret_cast<const half8*>(Xh + (size_t)grow * 128 + kc * 32 + quad * 8)
                : z;
        }
        #pragma unroll
        for (int ct = 0; ct < 8; ct++) {
            int f = kc * 8 + ct;
            half8 bh = Bh[f * 64 + l];
            half8 bl = Bl[f * 64 + l];
            #pragma unroll
            for (int rt = 0; rt < 2; rt++) {
                acc[rt][ct] = __builtin_amdgcn_mfma_f32_16x16x32_f16(a[rt], bh, acc[rt][ct], 0, 0, 0);
                acc[rt][ct] = __builtin_amdgcn_mfma_f32_16x16x32_f16(a[rt], bl, acc[rt][ct], 0, 0, 0);
            }
        }
    }

    #pragma unroll
    for (int rt = 0; rt < 2; rt++) {
        #pragma unroll
        for (int r = 0; r < 4; r++) {
            int grow = row0 + w * 32 + rt * 16 + quad * 4 + r;
            if (grow < N) {
                float s = srow[grow];
                #pragma unroll
                for (int ct = 0; ct < 8; ct++)
                    Y[(size_t)grow * 128 + ct * 16 + m] = (_Float16)(acc[rt][ct][r] * s);
            }
        }
    }
}

// ---------------------------------------------------------------- gather-aggregate layer 2 (round-11 control)
__global__ __launch_bounds__(256) void gather_agg(const __half* __restrict__ Hh,
                                                  const int* __restrict__ row_ptr,
                                                  const int* __restrict__ col,
                                                  const float* __restrict__ sin_,
                                                  const float* __restrict__ bias,
                                                  __half* __restrict__ Yh, int N)
{
    int node = blockIdx.x * 4 + (threadIdx.x >> 6);
    if (node >= N) return;
    int lane = threadIdx.x & 63;
    int beg = row_ptr[2 * node], end = row_ptr[2 * node + 1];
    const __half2* H2 = reinterpret_cast<const __half2*>(Hh);
    float2 acc0 = make_float2(0.f, 0.f);
    float2 acc1 = make_float2(0.f, 0.f);
    int i = beg;
    for (; i + 3 < end; i += 4) {
        int s0 = col[i], s1 = col[i + 1], s2 = col[i + 2], s3 = col[i + 3];
        __half2 v0 = H2[((size_t)s0 << 6) | lane];
        __half2 v1 = H2[((size_t)s1 << 6) | lane];
        __half2 v2 = H2[((size_t)s2 << 6) | lane];
        __half2 v3 = H2[((size_t)s3 << 6) | lane];
        float2 f0 = __half22float2(v0), f1 = __half22float2(v1);
        float2 f2 = __half22float2(v2), f3 = __half22float2(v3);
        acc0.x += f0.x + f1.x; acc0.y += f0.y + f1.y;
        acc1.x += f2.x + f3.x; acc1.y += f2.y + f3.y;
    }
    for (; i < end; i++) {
        int s = col[i];
        float2 f = __half22float2(H2[((size_t)s << 6) | lane]);
        acc0.x += f.x; acc0.y += f.y;
    }
    float sc = sin_[node];
    float2 b = reinterpret_cast<const float2*>(bias)[lane];
    float ox = fmaxf((acc0.x + acc1.x) * sc + b.x, 0.f);
    float oy = fmaxf((acc0.y + acc1.y) * sc + b.y, 0.f);
    reinterpret_cast<__half2*>(Yh)[((size_t)node << 6) | lane] = __floats2half2_rn(ox, oy);
}

// ---------------------------------------------------------------- classifier (fp16 in)
__global__ __launch_bounds__(256) void classifier(const __half* __restrict__ Hh,
                                                  const float* __restrict__ Wc,
                                                  const float* __restrict__ bc,
                                                  float* __restrict__ out, int N)
{
    __shared__ float4 Wcs[128];   // row k -> 4 cols
    for (int i = threadIdx.x; i < 128; i += 256)
        Wcs[i] = reinterpret_cast<const float4*>(Wc)[i];
    __syncthreads();
    int i = blockIdx.x * 256 + threadIdx.x;
    if (i < N) {
        float4 acc = reinterpret_cast<const float4*>(bc)[0];
        const __half2* h2 = reinterpret_cast<const __half2*>(Hh) + (size_t)i * 64;
        #pragma unroll
        for (int j = 0; j < 64; j++) {
            float2 f = __half22float2(h2[j]);
            float4 w0 = Wcs[2 * j], w1 = Wcs[2 * j + 1];
            acc.x += f.x * w0.x + f.y * w1.x;
            acc.y += f.x * w0.y + f.y * w1.y;
            acc.z += f.x * w0.z + f.y * w1.z;
            acc.w += f.x * w0.w + f.y * w1.w;
        }
        reinterpret_cast<float4*>(out)[i] = acc;
    }
}

// ---------------------------------------------------------------- launch
extern "C" void kernel_launch(void* const* d_in, const int* in_sizes, int n_in,
                              void* d_out, int out_size, void* d_ws, size_t ws_size,
                              hipStream_t stream)
{
    const float* features = (const float*)d_in[0];
    const int*   src      = (const int*)d_in[1];
    const int*   dst      = (const int*)d_in[2];
    const float* W1       = (const float*)d_in[3];
    const float* b1       = (const float*)d_in[4];
    const float* W2       = (const float*)d_in[5];
    const float* b2       = (const float*)d_in[6];
    const float* Wc       = (const float*)d_in[7];
    const float* bc       = (const float*)d_in[8];
    float* out = (float*)d_out;

    char* ws = (char*)d_ws;
    const size_t MB = 1 << 20;
    int* curD  = (int*)(ws + 0);                     // NBUK ints
    int* curS  = (int*)(ws + 1024);                  // NBUK ints
    float* sout    = (float*)(ws + 1 * MB);          // N floats
    float* sin_    = (float*)(ws + 2 * MB);          // N floats
    int*   row_ptr = (int*)(ws + 3 * MB);            // 2N ints (beg/end pairs)
    int*   col     = (int*)(ws + 4 * MB);            // NBUK*CAP ints (7.2 MB, strided)
    int*   bukD    = (int*)(ws + 12 * MB);           // NBUK*CAP packed ints (7.2 MB)
    int*   bukS    = (int*)(ws + 20 * MB);           // NBUK*CAP ints (7.2 MB)
    _Float16* Whi1 = (_Float16*)(ws + 28 * MB);              // 32 KB
    _Float16* Wlo1 = (_Float16*)(ws + 28 * MB + 32 * 1024);  // 32 KB
    _Float16* Whi2 = (_Float16*)(ws + 28 * MB + 64 * 1024);  // 32 KB
    _Float16* Wlo2 = (_Float16*)(ws + 28 * MB + 96 * 1024);  // 32 KB
    _Float16* hMsg = (_Float16*)(ws + 29 * MB);      // [N+1,128] fp16 (25.6 MB + pad row)
    _Float16* hA   = (_Float16*)(ws + 55 * MB);      // [N,128] fp16 (25.6 MB)

    const int N = N_NODES;

    // ---- K1: init cursors/pad + pack weights
    init_pack<<<129, 256, 0, stream>>>(curD, curS, hMsg + (size_t)N * F,
                                       W1, W2, Whi1, Wlo1, Whi2, Wlo2);

    // ---- K2: partition (196) + gemm1 unscaled (391 x 256 rows)
    part_gemm1<<<NBUK + 391, 512, 0, stream>>>(src, dst, curD, curS, bukD, bukS,
                                               features, Whi1, Wlo1, hMsg, N);

    // ---- K3: csr (196) + out-degree (196)
    csr_deg<<<2 * NBUK, 512, 0, stream>>>(bukD, bukS, curD, curS,
                                          row_ptr, sin_, sout, col);

    // ---- layer 1 aggregate (per-edge sout)
    gather_agg_s<<<(N + 3) / 4, 256, 0, stream>>>((const __half*)hMsg, row_ptr, col,
                                                  sout, sin_, b1, (__half*)hA, N);

    // ---- layer 2
    gemm_mfma_f16<<<(N + 127) / 128, 256, 0, stream>>>(hA, Whi2, Wlo2, sout, hMsg, N);
    gather_agg<<<(N + 3) / 4, 256, 0, stream>>>((const __half*)hMsg, row_ptr, col,
                                                sin_, b2, (__half*)hA, N);

    // ---- classifier
    classifier<<<(N + 255) / 256, 256, 0, stream>>>((const __half*)hA, Wc, bc, out, N);
}

// Round 13
// 328.592 us; speedup vs baseline: 1.2540x; 1.0449x over previous
//
#include <hip/hip_runtime.h>
#include <hip/hip_fp16.h>
#include <math.h>

#define N_NODES 100000
#define N_EDGES 1600000
#define F 128
#define NBUK 196        // ceil(N_NODES / 512)
#define BSH 9           // bucket = node >> 9  (512 nodes per bucket)
#define BSZ 512
#define CAP 9216        // fixed bucket region capacity (mean 8163, sd ~90)

typedef _Float16 half8 __attribute__((ext_vector_type(8)));
typedef _Float16 half4v __attribute__((ext_vector_type(4)));
typedef float    f32x4 __attribute__((ext_vector_type(4)));

// ---------------------------------------------------------------- K1: init cursors + pad row + sout[N] + pack W1/W2
__global__ __launch_bounds__(256) void init_pack(int* __restrict__ curD,
                                                 int* __restrict__ curS,
                                                 _Float16* __restrict__ padrow,
                                                 float* __restrict__ sout,
                                                 const float* __restrict__ W1,
                                                 const float* __restrict__ W2,
                                                 _Float16* __restrict__ hi1,
                                                 _Float16* __restrict__ lo1,
                                                 _Float16* __restrict__ hi2,
                                                 _Float16* __restrict__ lo2)
{
    int t = threadIdx.x;
    if (blockIdx.x == 0) {
        if (t < NBUK) { curD[t] = t * CAP; curS[t] = t * CAP; }
        if (t < 16) reinterpret_cast<int4*>(padrow)[t] = make_int4(0, 0, 0, 0);
        if (t == 255) sout[N_NODES] = 0.f;   // pad entry for gather zero-row path
        return;
    }
    int gidx = (blockIdx.x - 1) * 256 + t;
    const float* W = (gidx < 16384) ? W1 : W2;
    _Float16* hi = (gidx < 16384) ? hi1 : hi2;
    _Float16* lo = (gidx < 16384) ? lo1 : lo2;
    int idx = gidx & 16383;
    int f = idx >> 9, r = idx & 511;
    int l = r >> 3, j = r & 7;
    int kc = f >> 3, ct = f & 7;
    int k = kc * 32 + (l >> 4) * 8 + j;
    int n = ct * 16 + (l & 15);
    float w = W[k * 128 + n];
    _Float16 h = (_Float16)w;
    hi[idx] = h;
    lo[idx] = (_Float16)(w - (float)h);
}

// ---------------------------------------------------------------- K2: partition (196 blocks) + gemm1 (391 blocks)
// partition: bukD packed (d&511)<<17|s, bukS packed (s&511) as u16.
// gemm1: Yh = fp16(fp16(X) @ W1), W exact via hi+lo (2 MFMA terms), unscaled.
__global__ __launch_bounds__(512) void part_gemm1(const int* __restrict__ src,
                                                  const int* __restrict__ dst,
                                                  int* __restrict__ curD,
                                                  int* __restrict__ curS,
                                                  int* __restrict__ bukD,
                                                  unsigned short* __restrict__ bukS,
                                                  const float* __restrict__ X,
                                                  const _Float16* __restrict__ Whi,
                                                  const _Float16* __restrict__ Wlo,
                                                  _Float16* __restrict__ Y, int N)
{
    __shared__ int hd[NBUK], hs[NBUK], bd[NBUK], bs[NBUK], cd[NBUK], cs[NBUK];
    const int tid = threadIdx.x;

    if (blockIdx.x < NBUK) {
        // ---------------- partition ----------------
        const int chunk = (((N_EDGES + NBUK - 1) / NBUK) + 3) & ~3;
        const int beg = blockIdx.x * chunk;
        const int end = min(beg + chunk, N_EDGES);
        if (beg >= end) return;
        if (tid < NBUK) { hd[tid] = 0; hs[tid] = 0; cd[tid] = 0; cs[tid] = 0; }
        __syncthreads();
        const int b4 = beg >> 2, e4 = end >> 2;
        for (int i = b4 + tid; i < e4; i += 512) {
            int4 d = reinterpret_cast<const int4*>(dst)[i];
            int4 s = reinterpret_cast<const int4*>(src)[i];
            atomicAdd(&hd[d.x >> BSH], 1); atomicAdd(&hd[d.y >> BSH], 1);
            atomicAdd(&hd[d.z >> BSH], 1); atomicAdd(&hd[d.w >> BSH], 1);
            atomicAdd(&hs[s.x >> BSH], 1); atomicAdd(&hs[s.y >> BSH], 1);
            atomicAdd(&hs[s.z >> BSH], 1); atomicAdd(&hs[s.w >> BSH], 1);
        }
        __syncthreads();
        if (tid < NBUK) {
            bd[tid] = hd[tid] ? atomicAdd(&curD[tid], hd[tid]) : 0;
            bs[tid] = hs[tid] ? atomicAdd(&curS[tid], hs[tid]) : 0;
        }
        __syncthreads();
        for (int e = beg + tid; e < end; e += 512) {
            int d = dst[e], s = src[e];
            int bin = d >> BSH;
            int r = atomicAdd(&cd[bin], 1);
            bukD[bd[bin] + r] = ((d & 511) << 17) | s;
            int bin2 = s >> BSH;
            int r2 = atomicAdd(&cs[bin2], 1);
            bukS[bs[bin2] + r2] = (unsigned short)(s & 511);
        }
        return;
    }

    // ---------------- gemm1: 512 thr = 8 waves x 32 rows = 256 rows/block ----------------
    const int l = tid & 63, w = tid >> 6;
    const int quad = l >> 4, m = l & 15;
    const int row0 = (blockIdx.x - NBUK) * 256;
    const half8* Bh = reinterpret_cast<const half8*>(Whi);
    const half8* Bl = reinterpret_cast<const half8*>(Wlo);

    f32x4 acc[2][8] = {};

    for (int kc = 0; kc < 4; kc++) {
        half8 ah[2];
        #pragma unroll
        for (int rt = 0; rt < 2; rt++) {
            int grow = row0 + w * 32 + rt * 16 + m;
            float4 xa = make_float4(0.f, 0.f, 0.f, 0.f), xb = xa;
            if (grow < N) {
                const float4* Xp = reinterpret_cast<const float4*>(X) + (size_t)grow * 32 + kc * 8 + quad * 2;
                xa = Xp[0]; xb = Xp[1];
            }
            ah[rt][0] = (_Float16)xa.x; ah[rt][1] = (_Float16)xa.y;
            ah[rt][2] = (_Float16)xa.z; ah[rt][3] = (_Float16)xa.w;
            ah[rt][4] = (_Float16)xb.x; ah[rt][5] = (_Float16)xb.y;
            ah[rt][6] = (_Float16)xb.z; ah[rt][7] = (_Float16)xb.w;
        }
        #pragma unroll
        for (int ct = 0; ct < 8; ct++) {
            int f = kc * 8 + ct;
            half8 bh = Bh[f * 64 + l];
            half8 bl = Bl[f * 64 + l];
            #pragma unroll
            for (int rt = 0; rt < 2; rt++) {
                acc[rt][ct] = __builtin_amdgcn_mfma_f32_16x16x32_f16(ah[rt], bh, acc[rt][ct], 0, 0, 0);
                acc[rt][ct] = __builtin_amdgcn_mfma_f32_16x16x32_f16(ah[rt], bl, acc[rt][ct], 0, 0, 0);
            }
        }
    }

    // C layout: col = l&15, row = quad*4 + reg
    #pragma unroll
    for (int rt = 0; rt < 2; rt++) {
        #pragma unroll
        for (int r = 0; r < 4; r++) {
            int grow = row0 + w * 32 + rt * 16 + quad * 4 + r;
            if (grow < N) {
                #pragma unroll
                for (int ct = 0; ct < 8; ct++)
                    Y[(size_t)grow * 128 + ct * 16 + m] = (_Float16)(acc[rt][ct][r]);
            }
        }
    }
}

// ---------------------------------------------------------------- K3: csr (bid<196) + out-degree (bid>=196)
__global__ __launch_bounds__(512) void csr_deg(const int* __restrict__ bukD,
                                               const unsigned short* __restrict__ bukS,
                                               const int* __restrict__ curD,
                                               const int* __restrict__ curS,
                                               int* __restrict__ row_ptr,
                                               float* __restrict__ sin_,
                                               float* __restrict__ sout,
                                               int* __restrict__ col)
{
    __shared__ int h[BSZ], sc[BSZ], cur[BSZ];
    const int tid = threadIdx.x;

    if (blockIdx.x >= NBUK) {
        // ---- out-degree from bukS (u16, value = s & 511) ----
        const int bid = blockIdx.x - NBUK;
        const int n0 = bid << BSH;
        const int lo = bid * CAP, hi = curS[bid];
        h[tid] = 0;
        __syncthreads();
        for (int i = lo + tid; i < hi; i += 512)
            atomicAdd(&h[bukS[i]], 1);
        __syncthreads();
        int node = n0 + tid;
        if (node < N_NODES) sout[node] = rsqrtf((float)max(h[tid], 1));
        return;
    }

    // ---- per-bucket CSR ----
    const int n0 = blockIdx.x << BSH;
    const int lo = blockIdx.x * CAP, hi = curD[blockIdx.x];
    h[tid] = 0;
    __syncthreads();
    for (int i = lo + tid; i < hi; i += 512)
        atomicAdd(&h[((unsigned)bukD[i]) >> 17], 1);
    __syncthreads();
    int own = h[tid];
    sc[tid] = own;
    __syncthreads();
    for (int off = 1; off < 512; off <<= 1) {
        int u = (tid >= off) ? sc[tid - off] : 0;
        __syncthreads();
        sc[tid] += u;
        __syncthreads();
    }
    int ex = sc[tid] - own;
    cur[tid] = ex;
    int node = n0 + tid;
    if (node < N_NODES) {
        row_ptr[2 * node]     = lo + ex;
        row_ptr[2 * node + 1] = lo + ex + own;
        sin_[node] = rsqrtf((float)max(own, 1));
    }
    __syncthreads();
    for (int i = lo + tid; i < hi; i += 512) {
        int p = bukD[i];
        int r = atomicAdd(&cur[((unsigned)p) >> 17], 1);
        col[lo + r] = p & 0x1FFFF;
    }
}

// ---------------------------------------------------------------- gather layer 1: 2 nodes/wave, 8B lanes, per-edge sout
// lanes 0-31 -> node 2w, lanes 32-63 -> node 2w+1; lane loads half4 (8 B).
// One load instruction covers 2 edges (one per wave-half). Pad -> zero row N.
__global__ __launch_bounds__(256) void gather_agg_s(const _Float16* __restrict__ Hh,
                                                    const int* __restrict__ row_ptr,
                                                    const int* __restrict__ col,
                                                    const float* __restrict__ sout,
                                                    const float* __restrict__ sin_,
                                                    const float* __restrict__ bias,
                                                    _Float16* __restrict__ Yh, int N)
{
    int wave = blockIdx.x * 4 + (threadIdx.x >> 6);
    int lane = threadIdx.x & 63;
    int sub  = lane & 31;
    int node = wave * 2 + (lane >> 5);
    if (node >= N) return;
    int beg = row_ptr[2 * node], end = row_ptr[2 * node + 1];
    const half4v* H4 = reinterpret_cast<const half4v*>(Hh);
    float a0 = 0.f, a1 = 0.f, a2 = 0.f, a3 = 0.f;
    for (int i = beg; i < end; i += 4) {
        int c[4];
        #pragma unroll
        for (int j = 0; j < 4; j++)
            c[j] = (i + j < end) ? col[i + j] : N_NODES;
        float w[4];
        #pragma unroll
        for (int j = 0; j < 4; j++) w[j] = sout[c[j]];
        half4v v[4];
        #pragma unroll
        for (int j = 0; j < 4; j++)
            v[j] = H4[((size_t)c[j] << 5) | sub];
        #pragma unroll
        for (int j = 0; j < 4; j++) {
            a0 = fmaf(w[j], (float)v[j][0], a0);
            a1 = fmaf(w[j], (float)v[j][1], a1);
            a2 = fmaf(w[j], (float)v[j][2], a2);
            a3 = fmaf(w[j], (float)v[j][3], a3);
        }
    }
    float scn = sin_[node];
    float4 b = reinterpret_cast<const float4*>(bias)[sub];
    half4v o;
    o[0] = (_Float16)fmaxf(fmaf(a0, scn, b.x), 0.f);
    o[1] = (_Float16)fmaxf(fmaf(a1, scn, b.y), 0.f);
    o[2] = (_Float16)fmaxf(fmaf(a2, scn, b.z), 0.f);
    o[3] = (_Float16)fmaxf(fmaf(a3, scn, b.w), 0.f);
    reinterpret_cast<half4v*>(Yh)[((size_t)node << 5) | sub] = o;
}

// ---------------------------------------------------------------- gather layer 2: 2 nodes/wave, 8B lanes, no edge scale
__global__ __launch_bounds__(256) void gather_agg(const _Float16* __restrict__ Hh,
                                                  const int* __restrict__ row_ptr,
                                                  const int* __restrict__ col,
                                                  const float* __restrict__ sin_,
                                                  const float* __restrict__ bias,
                                                  _Float16* __restrict__ Yh, int N)
{
    int wave = blockIdx.x * 4 + (threadIdx.x >> 6);
    int lane = threadIdx.x & 63;
    int sub  = lane & 31;
    int node = wave * 2 + (lane >> 5);
    if (node >= N) return;
    int beg = row_ptr[2 * node], end = row_ptr[2 * node + 1];
    const half4v* H4 = reinterpret_cast<const half4v*>(Hh);
    float a0 = 0.f, a1 = 0.f, a2 = 0.f, a3 = 0.f;
    for (int i = beg; i < end; i += 4) {
        int c[4];
        #pragma unroll
        for (int j = 0; j < 4; j++)
            c[j] = (i + j < end) ? col[i + j] : N_NODES;
        half4v v[4];
        #pragma unroll
        for (int j = 0; j < 4; j++)
            v[j] = H4[((size_t)c[j] << 5) | sub];
        #pragma unroll
        for (int j = 0; j < 4; j++) {
            a0 += (float)v[j][0];
            a1 += (float)v[j][1];
            a2 += (float)v[j][2];
            a3 += (float)v[j][3];
        }
    }
    float scn = sin_[node];
    float4 b = reinterpret_cast<const float4*>(bias)[sub];
    half4v o;
    o[0] = (_Float16)fmaxf(fmaf(a0, scn, b.x), 0.f);
    o[1] = (_Float16)fmaxf(fmaf(a1, scn, b.y), 0.f);
    o[2] = (_Float16)fmaxf(fmaf(a2, scn, b.z), 0.f);
    o[3] = (_Float16)fmaxf(fmaf(a3, scn, b.w), 0.f);
    reinterpret_cast<half4v*>(Yh)[((size_t)node << 5) | sub] = o;
}

// ---------------------------------------------------------------- MFMA GEMM, fp16 input, sout-scaled output (layer 2)
__global__ __launch_bounds__(256) void gemm_mfma_f16(const _Float16* __restrict__ Xh,
                                                     const _Float16* __restrict__ Whi,
                                                     const _Float16* __restrict__ Wlo,
                                                     const float* __restrict__ srow,
                                                     _Float16* __restrict__ Y, int N)
{
    const int tid = threadIdx.x;
    const int l = tid & 63, w = tid >> 6;
    const int quad = l >> 4, m = l & 15;
    const int row0 = blockIdx.x * 128;
    const half8* Bh = reinterpret_cast<const half8*>(Whi);
    const half8* Bl = reinterpret_cast<const half8*>(Wlo);

    f32x4 acc[2][8] = {};

    for (int kc = 0; kc < 4; kc++) {
        half8 a[2];
        #pragma unroll
        for (int rt = 0; rt < 2; rt++) {
            int grow = row0 + w * 32 + rt * 16 + m;
            half8 z = {};
            a[rt] = (grow < N)
                ? *reinterpret_cast<const half8*>(Xh + (size_t)grow * 128 + kc * 32 + quad * 8)
                : z;
        }
        #pragma unroll
        for (int ct = 0; ct < 8; ct++) {
            int f = kc * 8 + ct;
            half8 bh = Bh[f * 64 + l];
            half8 bl = Bl[f * 64 + l];
            #pragma unroll
            for (int rt = 0; rt < 2; rt++) {
                acc[rt][ct] = __builtin_amdgcn_mfma_f32_16x16x32_f16(a[rt], bh, acc[rt][ct], 0, 0, 0);
                acc[rt][ct] = __builtin_amdgcn_mfma_f32_16x16x32_f16(a[rt], bl, acc[rt][ct], 0, 0, 0);
            }
        }
    }

    #pragma unroll
    for (int rt = 0; rt < 2; rt++) {
        #pragma unroll
        for (int r = 0; r < 4; r++) {
            int grow = row0 + w * 32 + rt * 16 + quad * 4 + r;
            if (grow < N) {
                float s = srow[grow];
                #pragma unroll
                for (int ct = 0; ct < 8; ct++)
                    Y[(size_t)grow * 128 + ct * 16 + m] = (_Float16)(acc[rt][ct][r] * s);
            }
        }
    }
}

// ---------------------------------------------------------------- classifier (fp16 in)
__global__ __launch_bounds__(256) void classifier(const __half* __restrict__ Hh,
                                                  const float* __restrict__ Wc,
                                                  const float* __restrict__ bc,
                                                  float* __restrict__ out, int N)
{
    __shared__ float4 Wcs[128];   // row k -> 4 cols
    for (int i = threadIdx.x; i < 128; i += 256)
        Wcs[i] = reinterpret_cast<const float4*>(Wc)[i];
    __syncthreads();
    int i = blockIdx.x * 256 + threadIdx.x;
    if (i < N) {
        float4 acc = reinterpret_cast<const float4*>(bc)[0];
        const __half2* h2 = reinterpret_cast<const __half2*>(Hh) + (size_t)i * 64;
        #pragma unroll
        for (int j = 0; j < 64; j++) {
            float2 f = __half22float2(h2[j]);
            float4 w0 = Wcs[2 * j], w1 = Wcs[2 * j + 1];
            acc.x += f.x * w0.x + f.y * w1.x;
            acc.y += f.x * w0.y + f.y * w1.y;
            acc.z += f.x * w0.z + f.y * w1.z;
            acc.w += f.x * w0.w + f.y * w1.w;
        }
        reinterpret_cast<float4*>(out)[i] = acc;
    }
}

// ---------------------------------------------------------------- launch
extern "C" void kernel_launch(void* const* d_in, const int* in_sizes, int n_in,
                              void* d_out, int out_size, void* d_ws, size_t ws_size,
                              hipStream_t stream)
{
    const float* features = (const float*)d_in[0];
    const int*   src      = (const int*)d_in[1];
    const int*   dst      = (const int*)d_in[2];
    const float* W1       = (const float*)d_in[3];
    const float* b1       = (const float*)d_in[4];
    const float* W2       = (const float*)d_in[5];
    const float* b2       = (const float*)d_in[6];
    const float* Wc       = (const float*)d_in[7];
    const float* bc       = (const float*)d_in[8];
    float* out = (float*)d_out;

    char* ws = (char*)d_ws;
    const size_t MB = 1 << 20;
    int* curD  = (int*)(ws + 0);                     // NBUK ints
    int* curS  = (int*)(ws + 1024);                  // NBUK ints
    float* sout    = (float*)(ws + 1 * MB);          // N+1 floats
    float* sin_    = (float*)(ws + 2 * MB);          // N floats
    int*   row_ptr = (int*)(ws + 3 * MB);            // 2N ints (beg/end pairs)
    int*   col     = (int*)(ws + 4 * MB);            // NBUK*CAP ints (7.2 MB, strided)
    int*   bukD    = (int*)(ws + 12 * MB);           // NBUK*CAP packed ints (7.2 MB)
    unsigned short* bukS = (unsigned short*)(ws + 20 * MB);  // NBUK*CAP u16 (3.6 MB)
    _Float16* Whi1 = (_Float16*)(ws + 24 * MB);              // 32 KB
    _Float16* Wlo1 = (_Float16*)(ws + 24 * MB + 32 * 1024);  // 32 KB
    _Float16* Whi2 = (_Float16*)(ws + 24 * MB + 64 * 1024);  // 32 KB
    _Float16* Wlo2 = (_Float16*)(ws + 24 * MB + 96 * 1024);  // 32 KB
    _Float16* hMsg = (_Float16*)(ws + 25 * MB);      // [N+1,128] fp16 (25.6 MB + pad row)
    _Float16* hA   = (_Float16*)(ws + 52 * MB);      // [N,128] fp16 (25.6 MB)

    const int N = N_NODES;
    const int NGB = (N / 2 + 3) / 4;                 // 12500 gather blocks (8 nodes each)

    // ---- K1: init cursors/pad/sout[N] + pack weights
    init_pack<<<129, 256, 0, stream>>>(curD, curS, hMsg + (size_t)N * F, sout,
                                       W1, W2, Whi1, Wlo1, Whi2, Wlo2);

    // ---- K2: partition (196) + gemm1 unscaled (391 x 256 rows)
    part_gemm1<<<NBUK + 391, 512, 0, stream>>>(src, dst, curD, curS, bukD, bukS,
                                               features, Whi1, Wlo1, hMsg, N);

    // ---- K3: csr (196) + out-degree (196)
    csr_deg<<<2 * NBUK, 512, 0, stream>>>(bukD, bukS, curD, curS,
                                          row_ptr, sin_, sout, col);

    // ---- layer 1 aggregate (per-edge sout, 2 nodes/wave)
    gather_agg_s<<<NGB, 256, 0, stream>>>(hMsg, row_ptr, col, sout, sin_, b1, hA, N);

    // ---- layer 2
    gemm_mfma_f16<<<(N + 127) / 128, 256, 0, stream>>>(hA, Whi2, Wlo2, sout, hMsg, N);
    gather_agg<<<NGB, 256, 0, stream>>>(hMsg, row_ptr, col, sin_, b2, hA, N);

    // ---- classifier
    classifier<<<(N + 255) / 256, 256, 0, stream>>>((const __half*)hA, Wc, bc, out, N);
}